// Round 1
// baseline (277.277 us; speedup 1.0000x reference)
//
#include <hip/hip_runtime.h>

#define DEPTH 8
#define LBITS 256            // 2^DEPTH
#define HHH 512
#define WWW 512
#define HW (HHH * WWW)       // 262144 pixels
#define VEC4 (HW / 4)        // 65536 float4 pixel-vectors = 2^16
#define NV4 (LBITS * VEC4)   // 2^24 total f32x4 output elements
#define BLOCK 256
#define BLOCKS 8192
#define SPAN (BLOCKS * BLOCK)     // 2^21 -- multiple of VEC4, so v is loop-invariant
#define ITERS (NV4 / SPAN)        // 8
#define TSTEP (SPAN / VEC4)       // 32 -- t advance per iteration

typedef float f32x4 __attribute__((ext_vector_type(4)));

// rng[i] = bitrev8(i)/256 exactly (van der Corput). Computed in-register:
// th > rng[a]  <=>  th*256 > (float)(brev8(a)) -- both scalings are exact
// powers of two, so the strict compare is bit-identical.
//
// Store pattern clones the 6.4 TB/s rocclr fill: one linear grid-stride sweep,
// each iteration the whole grid writes one contiguous 32 MiB stripe.
// NEW this round: nontemporal stores -- the 256 MiB output stream is never
// re-read by this kernel, so 'nt' keeps it from churning the 32 MiB L2 as
// dirty write-back lines (the rocclr fill's effective policy).
__global__ __launch_bounds__(BLOCK) void nsbuilder_kernel(
    const float* __restrict__ src_ns,
    const float* __restrict__ src_st,
    const float* __restrict__ nslen,
    float* __restrict__ out)
{
    const int idx0 = blockIdx.x * BLOCK + threadIdx.x;  // f32x4 linear index
    const int v    = idx0 & (VEC4 - 1);                 // pixel-vector (loop-invariant)
    int       t    = idx0 >> 16;                        // bit-plane, starts 0..31

    const f32x4 ns4 = ((const f32x4*)src_ns)[v];
    const f32x4 st4 = ((const f32x4*)src_st)[v];
    const f32x4 nl4 = ((const f32x4*)nslen)[v];

    // new_ns_len is integer-valued; int compare t < nl is exact
    const int   nl[4]  = {(int)nl4.x, (int)nl4.y, (int)nl4.z, (int)nl4.w};
    // thresholds pre-scaled by 256 (exact exponent shift)
    const float nsv[4] = {ns4.x * 256.0f, ns4.y * 256.0f, ns4.z * 256.0f, ns4.w * 256.0f};
    const float stv[4] = {st4.x * 256.0f, st4.y * 256.0f, st4.z * 256.0f, st4.w * 256.0f};

    f32x4* outp = (f32x4*)out + idx0;

    #pragma unroll
    for (int i = 0; i < ITERS; ++i, t += TSTEP) {
        float o[4];
        #pragma unroll
        for (int c = 0; c < 4; ++c) {
            const bool ns = t < nl[c];
            const int  a  = ns ? t : (t - nl[c]);                // in [0,255]
            const float rv = (float)(__brev((unsigned)a) >> 24); // = 256*rng[a]
            const float th = ns ? nsv[c] : stv[c];
            o[c] = (th > rv) ? 1.0f : 0.0f;
        }
        f32x4 o4 = {o[0], o[1], o[2], o[3]};
        __builtin_nontemporal_store(o4, outp + (size_t)i * SPAN);  // nt: bypass L2 retention
    }
}

extern "C" void kernel_launch(void* const* d_in, const int* in_sizes, int n_in,
                              void* d_out, int out_size, void* d_ws, size_t ws_size,
                              hipStream_t stream) {
    const float* src_ns = (const float*)d_in[0];
    const float* src_st = (const float*)d_in[1];
    const float* nslen  = (const float*)d_in[2];
    // d_in[3] (rng) unused: computed in-register (exact van der Corput closed form)
    float* out = (float*)d_out;

    nsbuilder_kernel<<<dim3(BLOCKS), dim3(BLOCK), 0, stream>>>(src_ns, src_st, nslen, out);
}

// Round 2
// 260.232 us; speedup vs baseline: 1.0655x; 1.0655x over previous
//
#include <hip/hip_runtime.h>

#define DEPTH 8
#define LBITS 256            // 2^DEPTH
#define HHH 512
#define WWW 512
#define HW (HHH * WWW)       // 262144 pixels
#define VEC4 (HW / 4)        // 65536 float4 pixel-vectors = 2^16
#define NV4 (LBITS * VEC4)   // 2^24 total f32x4 output elements
#define BLOCK 256
#define BLOCKS 8192
#define SPAN (BLOCKS * BLOCK)     // 2^21 -- multiple of VEC4, so v is loop-invariant
#define ITERS (NV4 / SPAN)        // 8
#define TSTEP (SPAN / VEC4)       // 32 -- t advance per iteration

typedef float f32x4 __attribute__((ext_vector_type(4)));

// rng[i] = bitrev8(i)/256 exactly (van der Corput). Computed in-register:
// th > rng[a]  <=>  th*256 > (float)(brev8(a)) -- both scalings are exact
// powers of two, so the strict compare is bit-identical.
//
// Store pattern clones the 6.4 TB/s rocclr fill: one linear grid-stride sweep,
// each iteration the whole grid writes one contiguous 32 MiB stripe.
// R1 lesson: __builtin_nontemporal_store regressed +18us (277.3 vs 259.3) --
// the default write-back streaming path IS the fast fill path on gfx950.
// Plain stores restored.
__global__ __launch_bounds__(BLOCK) void nsbuilder_kernel(
    const float* __restrict__ src_ns,
    const float* __restrict__ src_st,
    const float* __restrict__ nslen,
    float* __restrict__ out)
{
    const int idx0 = blockIdx.x * BLOCK + threadIdx.x;  // f32x4 linear index
    const int v    = idx0 & (VEC4 - 1);                 // pixel-vector (loop-invariant)
    int       t    = idx0 >> 16;                        // bit-plane, starts 0..31

    const f32x4 ns4 = ((const f32x4*)src_ns)[v];
    const f32x4 st4 = ((const f32x4*)src_st)[v];
    const f32x4 nl4 = ((const f32x4*)nslen)[v];

    // new_ns_len is integer-valued; int compare t < nl is exact
    const int   nl[4]  = {(int)nl4.x, (int)nl4.y, (int)nl4.z, (int)nl4.w};
    // thresholds pre-scaled by 256 (exact exponent shift)
    const float nsv[4] = {ns4.x * 256.0f, ns4.y * 256.0f, ns4.z * 256.0f, ns4.w * 256.0f};
    const float stv[4] = {st4.x * 256.0f, st4.y * 256.0f, st4.z * 256.0f, st4.w * 256.0f};

    f32x4* outp = (f32x4*)out + idx0;

    #pragma unroll
    for (int i = 0; i < ITERS; ++i, t += TSTEP) {
        float o[4];
        #pragma unroll
        for (int c = 0; c < 4; ++c) {
            const bool ns = t < nl[c];
            const int  a  = ns ? t : (t - nl[c]);                // in [0,255]
            const float rv = (float)(__brev((unsigned)a) >> 24); // = 256*rng[a]
            const float th = ns ? nsv[c] : stv[c];
            o[c] = (th > rv) ? 1.0f : 0.0f;
        }
        f32x4 o4 = {o[0], o[1], o[2], o[3]};
        outp[(size_t)i * SPAN] = o4;   // linear sweep, plain store (fill path)
    }
}

extern "C" void kernel_launch(void* const* d_in, const int* in_sizes, int n_in,
                              void* d_out, int out_size, void* d_ws, size_t ws_size,
                              hipStream_t stream) {
    const float* src_ns = (const float*)d_in[0];
    const float* src_st = (const float*)d_in[1];
    const float* nslen  = (const float*)d_in[2];
    // d_in[3] (rng) unused: computed in-register (exact van der Corput closed form)
    float* out = (float*)d_out;

    nsbuilder_kernel<<<dim3(BLOCKS), dim3(BLOCK), 0, stream>>>(src_ns, src_st, nslen, out);
}